// Round 1
// baseline (1538.544 us; speedup 1.0000x reference)
//
#include <hip/hip_runtime.h>
#include <hip/hip_bf16.h>
#include <cstdint>

// Problem dims (fixed)
#define S_   32
#define N_   400
#define G2_  16
#define R_   128
#define E_   64
#define KDIM (N_*G2_)   // 6400 = flattened (m,g)
#define COLS 1536       // 1024 (hW: g*64+e) + 512 (gh: j)
#define CAP  448        // max nnz per (s,n) row (mean 320, sigma ~17 -> 7.3 sigma)

__device__ __forceinline__ float sigmoidf_(float x) { return 1.0f / (1.0f + __expf(-x)); }

// ---------------------------------------------------------------------------
// Prologue: build WC[r][col] (combined W_t-reshape | W_hh^T), WihT[e][j],
// and copy h0/c0 into mutable state buffers.
//   WC[r][g*64+e]   = W_t[g*128 + r][e]
//   WC[r][1024 + j] = W_hh[j][r]
//   WihT[e][j]      = W_ih[j][e]
// ---------------------------------------------------------------------------
__global__ __launch_bounds__(256) void k_prep(
    const float* __restrict__ W_t, const float* __restrict__ W_hh,
    const float* __restrict__ W_ih, const float* __restrict__ h0,
    const float* __restrict__ c0,
    float* __restrict__ WC, float* __restrict__ WihT,
    float* __restrict__ h, float* __restrict__ c)
{
    const int total = 128*COLS + 128*512 + 2*N_*R_;
    for (int idx = blockIdx.x*256 + threadIdx.x; idx < total; idx += gridDim.x*256) {
        int i = idx;
        if (i < 128*COLS) {
            int r = i / COLS, col = i - r*COLS;
            float v;
            if (col < 1024) { int g = col >> 6, e = col & 63; v = W_t[(g*128 + r)*64 + e]; }
            else            { int j = col - 1024;             v = W_hh[j*128 + r]; }
            WC[i] = v;
        } else if (i < 128*COLS + 128*512) {
            i -= 128*COLS;
            int e = i / 512, j = i - e*512;
            WihT[i] = W_ih[j*128 + e];
        } else {
            i -= 128*COLS + 128*512;
            if (i < N_*R_) h[i] = h0[i];
            else           c[i - N_*R_] = c0[i - N_*R_];
        }
    }
}

// ---------------------------------------------------------------------------
// Sparse compaction of grids: per (s,n) row of 6400 f32, emit packed u32
// (idx<<16 | bf16(val)) pairs. One wave per row-pair -> deterministic order,
// no atomics. Grid: 1600 blocks x 256 (4 waves), 2 rows per wave.
// ---------------------------------------------------------------------------
__global__ __launch_bounds__(256) void k_compact(
    const float* __restrict__ grids, uint32_t* __restrict__ pairs,
    int* __restrict__ counts)
{
    int wave = (blockIdx.x << 2) | (threadIdx.x >> 6);   // 0..6399
    int lane = threadIdx.x & 63;
    for (int rr = 0; rr < 2; ++rr) {
        int row = wave*2 + rr;                           // 0..12799
        const float* src = grids + (size_t)row * KDIM;
        uint32_t*    dst = pairs + (size_t)row * CAP;
        int cnt = 0;                                     // wave-uniform
        for (int chunk = 0; chunk < KDIM; chunk += 64) {
            int idx = chunk + lane;
            float v = src[idx];
            bool nz = (v != 0.0f);
            unsigned long long mask = __ballot(nz);
            if (mask) {
                if (nz) {
                    int off = __popcll(mask & ((1ull << lane) - 1ull));
                    uint32_t bits = __float_as_uint(v);
                    bits += 0x7fffu + ((bits >> 16) & 1u);      // rne to bf16
                    int pos = cnt + off;
                    if (pos < CAP)
                        dst[pos] = ((uint32_t)idx << 16) | (bits >> 16);
                }
                cnt += __popcll(mask);
            }
        }
        if (lane == 0) counts[row] = (cnt < CAP) ? cnt : CAP;
    }
}

// ---------------------------------------------------------------------------
// Phase A: HG = h @ WC   ([400,128] @ [128,1536] f32)
// Grid: 300 blocks = 50 row-tiles(8) x 6 col-tiles(256). 256 threads = 1 col ea.
// ---------------------------------------------------------------------------
__global__ __launch_bounds__(256) void k_hg(
    const float* __restrict__ h, const float* __restrict__ WC,
    float* __restrict__ HG)
{
    __shared__ float hs[8][128];
    int rt = blockIdx.x / 6, ct = blockIdx.x - rt*6;
    int rowbase = rt * 8, colbase = ct * 256;
    #pragma unroll
    for (int k = 0; k < 4; ++k) {
        int i = k*256 + threadIdx.x;                    // 0..1023
        hs[i >> 7][i & 127] = h[(rowbase + (i >> 7))*R_ + (i & 127)];
    }
    __syncthreads();
    float acc[8] = {0,0,0,0,0,0,0,0};
    int col = colbase + threadIdx.x;
    const float* wcp = WC + col;
    #pragma unroll 4
    for (int r = 0; r < 128; ++r) {
        float wv = wcp[r * COLS];
        #pragma unroll
        for (int i = 0; i < 8; ++i) acc[i] += hs[i][r] * wv;
    }
    #pragma unroll
    for (int i = 0; i < 8; ++i) HG[(rowbase + i)*COLS + col] = acc[i];
}

// ---------------------------------------------------------------------------
// Phase B (per step): sparse tensor_pre gather, embeddings, gates, LSTM
// pointwise, output projection. Grid: 100 blocks x 256; wave w owns node
// n = blk*4 + w.
// ---------------------------------------------------------------------------
__global__ __launch_bounds__(256) void k_step(
    int s,
    const float* __restrict__ x,
    const float* __restrict__ W_in, const float* __restrict__ b_in,
    const float* __restrict__ b_t,
    const float* __restrict__ WihT, const float* __restrict__ b_ih,
    const float* __restrict__ b_hh,
    const float* __restrict__ HG,
    const uint32_t* __restrict__ pairs, const int* __restrict__ counts,
    float* __restrict__ h, float* __restrict__ c,
    const float* __restrict__ W_out, const float* __restrict__ b_out,
    float* __restrict__ out, int last)
{
    __shared__ float z[4][128];     // [iemb | temb] per node
    __shared__ float gl[4][512];    // gates per node
    __shared__ float hb[4][128];    // h_new per node

    int w = threadIdx.x >> 6, lane = threadIdx.x & 63;
    int n = (blockIdx.x << 2) | w;
    int row = s * N_ + n;

    // --- sparse tensor_pre: tp[e=lane] = sum val * HG[m][g*64+e] ---
    int cnt = counts[row];
    const uint32_t* P = pairs + (size_t)row * CAP;
    float acc[8] = {0,0,0,0,0,0,0,0};
    int p = 0;
    for (; p + 8 <= cnt; p += 8) {
        uint4 qa = *reinterpret_cast<const uint4*>(P + p);
        uint4 qb = *reinterpret_cast<const uint4*>(P + p + 4);
        uint32_t qs[8] = {qa.x, qa.y, qa.z, qa.w, qb.x, qb.y, qb.z, qb.w};
        #pragma unroll
        for (int u = 0; u < 8; ++u) {
            uint32_t q = qs[u];
            acc[u] += __uint_as_float(q << 16) *
                      HG[(q >> 20)*COLS + ((q >> 16) & 15u)*64 + lane];
        }
    }
    for (; p < cnt; ++p) {
        uint32_t q = P[p];
        acc[0] += __uint_as_float(q << 16) *
                  HG[(q >> 20)*COLS + ((q >> 16) & 15u)*64 + lane];
    }
    float tp = ((acc[0]+acc[1]) + (acc[2]+acc[3])) + ((acc[4]+acc[5]) + (acc[6]+acc[7]));

    // temb / iemb into LDS
    z[w][64 + lane] = fmaxf(tp + b_t[lane], 0.0f);
    float x0 = x[row*2 + 0], x1 = x[row*2 + 1];
    z[w][lane] = fmaxf(x0*W_in[lane] + x1*W_in[64 + lane] + b_in[lane], 0.0f);
    __syncthreads();

    // --- gates: [4 nodes,512] = z @ W_ih^T + b_ih + gh + b_hh ---
    int j0 = threadIdx.x, j1 = threadIdx.x + 256;
    float g0[4] = {0,0,0,0}, g1[4] = {0,0,0,0};
    for (int e = 0; e < 128; ++e) {
        float w0 = WihT[e*512 + j0], w1 = WihT[e*512 + j1];
        #pragma unroll
        for (int q = 0; q < 4; ++q) {
            float zv = z[q][e];
            g0[q] += zv * w0;
            g1[q] += zv * w1;
        }
    }
    float bi0 = b_ih[j0] + b_hh[j0], bi1 = b_ih[j1] + b_hh[j1];
    #pragma unroll
    for (int q = 0; q < 4; ++q) {
        int nq = (blockIdx.x << 2) | q;
        gl[q][j0] = g0[q] + bi0 + HG[nq*COLS + 1024 + j0];
        gl[q][j1] = g1[q] + bi1 + HG[nq*COLS + 1024 + j1];
    }
    __syncthreads();

    // --- LSTM pointwise (torch gate order i,f,g,o) ---
    #pragma unroll
    for (int rep = 0; rep < 2; ++rep) {
        int t = rep*256 + threadIdx.x;          // 0..511
        int q = t >> 7, r = t & 127;
        int nq = (blockIdx.x << 2) | q;
        float gi = gl[q][r], gf = gl[q][128 + r], gg = gl[q][256 + r], go = gl[q][384 + r];
        float cold = c[nq*R_ + r];
        float cn = sigmoidf_(gf)*cold + sigmoidf_(gi)*tanhf(gg);
        float hn = sigmoidf_(go)*tanhf(cn);
        c[nq*R_ + r] = cn;
        h[nq*R_ + r] = hn;
        hb[q][r] = hn;
        if (last) {
            out[S_*N_*5 + nq*R_ + r]            = hn;   // h_fin
            out[S_*N_*5 + N_*R_ + nq*R_ + r]    = cn;   // c_fin
        }
    }
    __syncthreads();

    // --- output projection: out[s,n,:] = h_new @ W_out + b_out ---
    if (threadIdx.x < 20) {
        int q = threadIdx.x / 5, o = threadIdx.x - (threadIdx.x / 5)*5;
        int nq = (blockIdx.x << 2) | q;
        float a = b_out[o];
        for (int r = 0; r < 128; ++r) a += hb[q][r] * W_out[r*5 + o];
        out[(s*N_ + nq)*5 + o] = a;
    }
}

// ---------------------------------------------------------------------------
extern "C" void kernel_launch(void* const* d_in, const int* in_sizes, int n_in,
                              void* d_out, int out_size, void* d_ws, size_t ws_size,
                              hipStream_t stream)
{
    const float* input_data = (const float*)d_in[0];
    const float* grids      = (const float*)d_in[1];
    const float* h0         = (const float*)d_in[2];
    const float* c0         = (const float*)d_in[3];
    const float* W_in       = (const float*)d_in[4];
    const float* b_in       = (const float*)d_in[5];
    const float* W_t        = (const float*)d_in[6];
    const float* b_t        = (const float*)d_in[7];
    const float* W_ih       = (const float*)d_in[8];
    const float* b_ih       = (const float*)d_in[9];
    const float* W_hh       = (const float*)d_in[10];
    const float* b_hh       = (const float*)d_in[11];
    const float* W_out      = (const float*)d_in[12];
    const float* b_out      = (const float*)d_in[13];
    float* out = (float*)d_out;

    // workspace layout (bytes); total ~27.2 MB
    char* ws = (char*)d_ws;
    float*    WC     = (float*)(ws + 0);          // 128*1536*4 = 786,432
    float*    WihT   = (float*)(ws + 786432);     // 128*512*4  = 262,144
    float*    HG     = (float*)(ws + 1048576);    // 400*1536*4 = 2,457,600
    float*    h      = (float*)(ws + 3506176);    // 400*128*4  = 204,800
    float*    c      = (float*)(ws + 3710976);    // 204,800
    int*      counts = (int*)  (ws + 3915776);    // 12800*4    = 51,200
    uint32_t* pairs  = (uint32_t*)(ws + 4194304); // 12800*448*4 = 22,937,600

    k_prep<<<dim3(512), dim3(256), 0, stream>>>(W_t, W_hh, W_ih, h0, c0, WC, WihT, h, c);
    k_compact<<<dim3(1600), dim3(256), 0, stream>>>(grids, pairs, counts);
    k_hg<<<dim3(300), dim3(256), 0, stream>>>(h, WC, HG);   // HG from initial h
    for (int s = 0; s < S_; ++s) {
        k_step<<<dim3(100), dim3(256), 0, stream>>>(
            s, input_data, W_in, b_in, b_t, WihT, b_ih, b_hh, HG, pairs, counts,
            h, c, W_out, b_out, out, (int)(s == S_ - 1));
        if (s < S_ - 1)
            k_hg<<<dim3(300), dim3(256), 0, stream>>>(h, WC, HG);
    }
}